// Round 8
// baseline (41.286 us; speedup 1.0000x reference)
//
#include <hip/hip_runtime.h>
#include <math.h>

#define NN 16384
#define DD 1024
#define HD 512

// ws layout (float units):
// [0]              : (int)   dynamic_k        (atomicExch in K2-b64, atomic read in phase C)
// [2]              : (int)   arrival counter  (zeroed K1, counted in K2)
// [4..14)          : (int)   neighbor_idx[10] (plain store K1; plain read K2 across boundary)
// [16..26)         : (float) sc[10] score accumulators (zeroed K1, atomicAdd K2, atomic read phase C)
// [64 .. +32*1024) : (float) up[32][1024]  u-partials (plain stores K1, summed K2)
// [32832 .. +32*512): (float) hp[32][512]  cnt-MLP hidden partials
#define WS_DK  0
#define WS_CTR 2
#define WS_NB  4
#define WS_SC  16
#define WS_UP  64
#define WS_HP  (64 + 32 * 1024)

// ============ K1: b0 = top-11 (+zero sc/ctr); b1..64 = u-partials; b65..96 = cnt partials ============
__global__ void __launch_bounds__(512) k1(const float* __restrict__ x,
                                          const float* __restrict__ W1,
                                          const float* __restrict__ Wc1,
                                          const float* __restrict__ sim,
                                          const int* __restrict__ tidx,
                                          float* __restrict__ ws,
                                          float* __restrict__ out) {
    const int t = threadIdx.x;              // 512
    const int b = blockIdx.x;               // 0..96
    const int lane = t & 63, wave = t >> 6;

    if (b > 0 && b <= 64) {
        // ---- u-partials: up[ic][j] = sum_{i in chunk ic} x[i] * W1_top[i][j] ----
        __shared__ float xs[32];
        const int idx = b - 1, ic = idx >> 1, jc = idx & 1;
        const int ibase = ic * 32;
        if (t < 32) xs[t] = x[ibase + t];
        __syncthreads();
        const int j = jc * 512 + t;
        float acc = 0.f;
        const float* W = W1 + (size_t)ibase * DD + j;
        #pragma unroll 8
        for (int ii = 0; ii < 32; ++ii) acc += xs[ii] * W[(size_t)ii * DD];
        ws[WS_UP + ic * DD + j] = acc;
        return;
    }
    if (b > 64) {
        // ---- cnt-MLP hidden partials: chunk c covers rows [c*32, c*32+32) ----
        __shared__ float xs[32];
        const int c = b - 65;
        const int ibase = c * 32;
        if (t < 32) xs[t] = x[ibase + t];
        __syncthreads();
        float acc = 0.f;
        const float* W = Wc1 + (size_t)ibase * HD + t;
        #pragma unroll 8
        for (int ii = 0; ii < 32; ++ii) acc += xs[ii] * W[(size_t)ii * HD];
        ws[WS_HP + c * HD + t] = acc;
        return;
    }

    // ---- b == 0: zero sc + arrival counter; deterministic top-11 (barrier-free per-wave + merge) ----
    if (t < 10) ws[WS_SC + t] = 0.f;
    if (t == 0) ((int*)ws)[WS_CTR] = 0;

    const int tgt = tidx[0];
    const float4* row4 = (const float4*)(sim + (size_t)tgt * NN);
    float vals[32];
    #pragma unroll
    for (int c = 0; c < 8; ++c) {
        float4 v = row4[c * 512 + t];
        vals[c * 4 + 0] = v.x; vals[c * 4 + 1] = v.y;
        vals[c * 4 + 2] = v.z; vals[c * 4 + 3] = v.w;
    }
    // vals[s=c*4+q] holds row[gi], gi = c*2048 + t*4 + q (monotone in s for fixed t)
    unsigned used = 0u;
    float bv = -INFINITY; int bs = 0;
    #pragma unroll
    for (int s = 0; s < 32; ++s) if (vals[s] > bv) { bv = vals[s]; bs = s; }

    __shared__ float wlv[8][11];
    __shared__ int   wli[8][11];

    // each wave extracts its own sorted top-11 from its 2048 candidates;
    // wave-synchronous (no block barrier), registers statically indexed (no scratch)
    for (int it = 0; it < 11; ++it) {
        float cv = bv;
        int   cg = (bs >> 2) * 2048 + t * 4 + (bs & 3);
        #pragma unroll
        for (int off = 32; off > 0; off >>= 1) {
            float ov = __shfl_down(cv, off);
            int   og = __shfl_down(cg, off);
            if (ov > cv || (ov == cv && og < cg)) { cv = ov; cg = og; }
        }
        const int wg = __shfl(cg, 0);        // broadcast winner idx to the wave
        if (lane == 0) { wlv[wave][it] = cv; wli[wave][it] = cg; }
        if (((wg >> 2) & 511) == t) {        // owner: mask slot via bitmask, rescan
            used |= 1u << (((wg >> 11) << 2) | (wg & 3));
            bv = -INFINITY; bs = 0;
            #pragma unroll
            for (int s = 0; s < 32; ++s) {
                float v = ((used >> s) & 1u) ? -INFINITY : vals[s];
                if (v > bv) { bv = v; bs = s; }
            }
        }
    }
    __syncthreads();
    if (t == 0) {
        // merge 8 sorted lists (val desc, idx asc) -> global top-11, then compaction
        int head[8] = {0, 0, 0, 0, 0, 0, 0, 0};
        int toplist[11];
        for (int it = 0; it < 11; ++it) {
            float fv = -INFINITY; int fg = 0x7fffffff; int fw = 0;
            #pragma unroll
            for (int w = 0; w < 8; ++w) {
                float v = wlv[w][head[w]];
                int   g = wli[w][head[w]];
                if (v > fv || (v == fv && g < fg)) { fv = v; fg = g; fw = w; }
            }
            toplist[it] = fg;
            head[fw] = head[fw] < 10 ? head[fw] + 1 : 10;
        }
        int cnt = 0;
        int* nbp = (int*)ws + WS_NB;
        for (int i = 0; i < 11 && cnt < 10; ++i) {
            int v = toplist[i];
            if (v != tgt) { nbp[cnt] = v; out[1034 + cnt] = (float)v; ++cnt; }
        }
    }
}

// ====== K2: b0..63 = 16-column GEMM + partial scores; b64 = cnt-final; last-done block = phase C ======
__global__ void __launch_bounds__(512) k2(const float* __restrict__ emb,
                                          const float* __restrict__ W1,
                                          const float* __restrict__ ba1,
                                          const float* __restrict__ W2,
                                          const float* __restrict__ ba2,
                                          const float* __restrict__ bc1,
                                          const float* __restrict__ Wc2,
                                          const float* __restrict__ bc2,
                                          float* __restrict__ ws,
                                          float* __restrict__ out) {
    const int t = threadIdx.x;              // 512
    const int b = blockIdx.x;               // 0..64
    const int lane = t & 63, wave = t >> 6;

    __shared__ int    nb[10];
    __shared__ float4 es4[10][256];         // 40 KB: 10 neighbor embeddings
    __shared__ float  red[32][16][11];      // 22.5 KB: [seg][jl][k]
    __shared__ float  ured[32][17];         // u-partials for this block's 16 columns
    __shared__ float  scr[16][10];
    __shared__ float  redp[8];
    __shared__ float  wl[10];
    __shared__ int    lastFlag;

    if (t < 10) nb[t] = ((const int*)ws)[WS_NB + t];   // K1 wrote: visible across boundary

    if (b == 64) {
        // ---- cnt-MLP finish -> dynamic_k (deterministic fixed-order + shfl tree) ----
        float s = 0.f;
        #pragma unroll 8
        for (int c = 0; c < 32; ++c) s += ws[WS_HP + c * HD + t];
        float v = fmaxf(s + bc1[t], 0.f) * Wc2[t];
        #pragma unroll
        for (int off = 32; off > 0; off >>= 1) v += __shfl_down(v, off);
        if (lane == 0) redp[wave] = v;
        __syncthreads();
        if (t == 0) {
            float z = bc2[0];
            #pragma unroll
            for (int w = 0; w < 8; ++w) z += redp[w];
            float frac = 1.f / (1.f + expf(-z));
            int dk = (int)floorf(frac * 10.f);
            dk = dk < 1 ? 1 : (dk > 10 ? 10 : dk);
            (void)atomicExch((int*)ws + WS_DK, dk);    // LLC store, no fence needed
        }
    } else {
        // ---- column-GEMM: block owns j in [b*16, b*16+16), full K = 1024 of W1_bot ----
        const int jl  = t & 15;                 // local column
        const int seg = t >> 4;                 // row segment 0..31 (32 rows each)
        const int jg  = b * 16 + jl;
        __syncthreads();                        // nb visible in LDS
        #pragma unroll
        for (int i = t; i < 2560; i += 512) {   // stage 10 x 1024 floats as float4
            int k = i >> 8, c = i & 255;
            es4[k][c] = ((const float4*)(emb + (size_t)nb[k] * DD))[c];
        }
        ured[seg][jl] = ws[WS_UP + seg * DD + jg];   // one u-partial per thread
        __syncthreads();

        float acc[10];
        #pragma unroll
        for (int k = 0; k < 10; ++k) acc[k] = 0.f;
        const float* Wb = W1 + (size_t)(1024 + seg * 32) * DD + jg;
        for (int c = 0; c < 8; ++c) {
            float4 ev[10];
            #pragma unroll
            for (int k = 0; k < 10; ++k) ev[k] = es4[k][seg * 8 + c];   // same addr / 16 lanes: broadcast
            #pragma unroll
            for (int q = 0; q < 4; ++q) {
                const float wb = Wb[(size_t)(c * 4 + q) * DD];          // 16 consecutive j: coalesced
                #pragma unroll
                for (int k = 0; k < 10; ++k)
                    acc[k] += reinterpret_cast<const float*>(&ev[k])[q] * wb;
            }
        }
        #pragma unroll
        for (int k = 0; k < 10; ++k) red[seg][jl][k] = acc[k];
        __syncthreads();

        // per-(column,k) fixed-order segment reduction + u + relu + W2  (160 threads)
        if (t < 160) {
            const int k = t >> 4, jj = t & 15;
            float s = 0.f;
            #pragma unroll 8
            for (int g = 0; g < 32; ++g) s += red[g][jj][k];
            float u = 0.f;
            #pragma unroll 8
            for (int g = 0; g < 32; ++g) u += ured[g][jj];
            scr[jj][k] = fmaxf(u + s + ba1[b * 16 + jj], 0.f) * W2[b * 16 + jj];
        }
        __syncthreads();
        if (t < 10) {                            // fixed-order column sum, one atomicAdd per k
            float s = 0.f;
            #pragma unroll
            for (int c = 0; c < 16; ++c) s += scr[c][t];
            atomicAdd(&ws[WS_SC + t], s);
        }
    }

    // ---- fence-free last-block election ----
    // __syncthreads drains each wave's vmcnt => this block's sc/dk atomics are
    // performed at the coherence point before t0's counter increment issues.
    __syncthreads();
    if (t == 0) lastFlag = (atomicAdd((int*)ws + WS_CTR, 1) == 64);
    __syncthreads();
    if (!lastFlag) return;

    // ================= phase C (runs on the last-arriving block) =================
    if (t == 0) {
        const int dk = atomicAdd((int*)ws + WS_DK, 0);      // coherent reads
        float sv[10];
        float m = -INFINITY;
        for (int k = 0; k < 10; ++k) {
            float s = atomicAdd(&ws[WS_SC + k], 0.f) + ba2[0];
            sv[k] = (k < dk) ? s : -INFINITY;
            if (sv[k] > m) m = sv[k];
        }
        float sum = 0.f;
        for (int k = 0; k < 10; ++k) { sv[k] = expf(sv[k] - m); sum += sv[k]; }
        for (int k = 0; k < 10; ++k) wl[k] = sv[k] / sum;
    }
    __syncthreads();
    #pragma unroll
    for (int jj = 0; jj < 2; ++jj) {
        const int j = t + jj * 512;
        float a = 0.f;
        #pragma unroll
        for (int k = 0; k < 10; ++k) a += wl[k] * emb[(size_t)nb[k] * DD + j];
        out[j] = a;
    }
    if (t < 10) { out[1024 + t] = wl[t]; out[1044 + t] = wl[t]; }
}

extern "C" void kernel_launch(void* const* d_in, const int* in_sizes, int n_in,
                              void* d_out, int out_size, void* d_ws, size_t ws_size,
                              hipStream_t stream) {
    const float* x    = (const float*)d_in[0];   // target_embedding [1024]
    const float* emb  = (const float*)d_in[1];   // all_embeddings [16384,1024]
    const float* sim  = (const float*)d_in[2];   // similarity_matrix [16384,16384]
    const float* W1   = (const float*)d_in[3];   // W_att1 [2048,1024]
    const float* ba1  = (const float*)d_in[4];   // b_att1 [1024]
    const float* W2   = (const float*)d_in[5];   // W_att2 [1024]
    const float* ba2  = (const float*)d_in[6];   // b_att2 [1]
    const float* Wc1  = (const float*)d_in[7];   // W_cnt1 [1024,512]
    const float* bc1  = (const float*)d_in[8];   // b_cnt1 [512]
    const float* Wc2  = (const float*)d_in[9];   // W_cnt2 [512]
    const float* bc2  = (const float*)d_in[10];  // b_cnt2 [1]
    const int*   tidx = (const int*)d_in[11];    // target_idx [1]
    float* out = (float*)d_out;
    float* ws  = (float*)d_ws;

    hipLaunchKernelGGL(k1, dim3(97), dim3(512), 0, stream, x, W1, Wc1, sim, tidx, ws, out);
    hipLaunchKernelGGL(k2, dim3(65), dim3(512), 0, stream,
                       emb, W1, ba1, W2, ba2, bc1, Wc2, bc2, ws, out);
}

// Round 9
// 38.098 us; speedup vs baseline: 1.0837x; 1.0837x over previous
//
#include <hip/hip_runtime.h>
#include <math.h>

#define NN 16384
#define DD 1024
#define HD 512

// ws layout (float units):
// [0]              : (int)   dynamic_k        (plain store K2, plain read K3)
// [4..14)          : (int)   neighbor_idx[10] (plain store K1)
// [16..26)         : (float) sc[10] score accumulators (zeroed K1, atomicAdd K2, read K3)
// [64 .. +32*1024) : (float) up[32][1024]  u-partials (plain stores K1, summed K2)
// [32832 .. +32*512): (float) hp[32][512]  cnt-MLP hidden partials
#define WS_DK  0
#define WS_NB  4
#define WS_SC  16
#define WS_UP  64
#define WS_HP  (64 + 32 * 1024)

// ============ K1: b0 = top-11 (+zero sc); b1..64 = u-partials; b65..96 = cnt partials ============
__global__ void __launch_bounds__(512) k1(const float* __restrict__ x,
                                          const float* __restrict__ W1,
                                          const float* __restrict__ Wc1,
                                          const float* __restrict__ sim,
                                          const int* __restrict__ tidx,
                                          float* __restrict__ ws,
                                          float* __restrict__ out) {
    const int t = threadIdx.x;              // 512
    const int b = blockIdx.x;               // 0..96
    const int lane = t & 63, wave = t >> 6;

    if (b > 0 && b <= 64) {
        // ---- u-partials: up[ic][j] = sum_{i in chunk ic} x[i] * W1_top[i][j] ----
        __shared__ float xs[32];
        const int idx = b - 1, ic = idx >> 1, jc = idx & 1;
        const int ibase = ic * 32;
        if (t < 32) xs[t] = x[ibase + t];
        __syncthreads();
        const int j = jc * 512 + t;
        float acc = 0.f;
        const float* W = W1 + (size_t)ibase * DD + j;
        #pragma unroll 8
        for (int ii = 0; ii < 32; ++ii) acc += xs[ii] * W[(size_t)ii * DD];
        ws[WS_UP + ic * DD + j] = acc;
        return;
    }
    if (b > 64) {
        // ---- cnt-MLP hidden partials: chunk c covers rows [c*32, c*32+32) ----
        __shared__ float xs[32];
        const int c = b - 65;
        const int ibase = c * 32;
        if (t < 32) xs[t] = x[ibase + t];
        __syncthreads();
        float acc = 0.f;
        const float* W = Wc1 + (size_t)ibase * HD + t;
        #pragma unroll 8
        for (int ii = 0; ii < 32; ++ii) acc += xs[ii] * W[(size_t)ii * HD];
        ws[WS_HP + c * HD + t] = acc;
        return;
    }

    // ---- b == 0: zero sc + deterministic top-11 (barrier-free per-wave + merge) ----
    if (t < 10) ws[WS_SC + t] = 0.f;

    const int tgt = tidx[0];
    const float4* row4 = (const float4*)(sim + (size_t)tgt * NN);
    float vals[32];
    #pragma unroll
    for (int c = 0; c < 8; ++c) {
        float4 v = row4[c * 512 + t];
        vals[c * 4 + 0] = v.x; vals[c * 4 + 1] = v.y;
        vals[c * 4 + 2] = v.z; vals[c * 4 + 3] = v.w;
    }
    // vals[s=c*4+q] holds row[gi], gi = c*2048 + t*4 + q (monotone in s for fixed t)
    unsigned used = 0u;
    float bv = -INFINITY; int bs = 0;
    #pragma unroll
    for (int s = 0; s < 32; ++s) if (vals[s] > bv) { bv = vals[s]; bs = s; }

    __shared__ float wlv[8][11];
    __shared__ int   wli[8][11];

    // each wave extracts its own sorted top-11 from its 2048 candidates;
    // wave-synchronous (no block barrier), registers statically indexed (no scratch)
    for (int it = 0; it < 11; ++it) {
        float cv = bv;
        int   cg = (bs >> 2) * 2048 + t * 4 + (bs & 3);
        #pragma unroll
        for (int off = 32; off > 0; off >>= 1) {
            float ov = __shfl_down(cv, off);
            int   og = __shfl_down(cg, off);
            if (ov > cv || (ov == cv && og < cg)) { cv = ov; cg = og; }
        }
        const int wg = __shfl(cg, 0);        // broadcast winner idx to the wave
        if (lane == 0) { wlv[wave][it] = cv; wli[wave][it] = cg; }
        if (((wg >> 2) & 511) == t) {        // owner: mask slot via bitmask, rescan
            used |= 1u << (((wg >> 11) << 2) | (wg & 3));
            bv = -INFINITY; bs = 0;
            #pragma unroll
            for (int s = 0; s < 32; ++s) {
                float v = ((used >> s) & 1u) ? -INFINITY : vals[s];
                if (v > bv) { bv = v; bs = s; }
            }
        }
    }
    __syncthreads();
    if (t == 0) {
        // merge 8 sorted lists (val desc, idx asc) -> global top-11, then compaction
        int head[8] = {0, 0, 0, 0, 0, 0, 0, 0};
        int toplist[11];
        for (int it = 0; it < 11; ++it) {
            float fv = -INFINITY; int fg = 0x7fffffff; int fw = 0;
            #pragma unroll
            for (int w = 0; w < 8; ++w) {
                float v = wlv[w][head[w]];
                int   g = wli[w][head[w]];
                if (v > fv || (v == fv && g < fg)) { fv = v; fg = g; fw = w; }
            }
            toplist[it] = fg;
            head[fw] = head[fw] < 10 ? head[fw] + 1 : 10;
        }
        int cnt = 0;
        int* nbp = (int*)ws + WS_NB;
        for (int i = 0; i < 11 && cnt < 10; ++i) {
            int v = toplist[i];
            if (v != tgt) { nbp[cnt] = v; out[1034 + cnt] = (float)v; ++cnt; }
        }
    }
}

// ====== K2: b0..63 = 16-column GEMM over W1_bot + partial scores; b64 = cnt-final ======
__global__ void __launch_bounds__(512) k2(const float* __restrict__ emb,
                                          const float* __restrict__ W1,
                                          const float* __restrict__ ba1,
                                          const float* __restrict__ W2,
                                          const float* __restrict__ bc1,
                                          const float* __restrict__ Wc2,
                                          const float* __restrict__ bc2,
                                          float* __restrict__ ws) {
    const int t = threadIdx.x;              // 512
    const int b = blockIdx.x;               // 0..64
    const int lane = t & 63, wave = t >> 6;

    __shared__ int    nb[10];
    __shared__ float4 es4[10][256];         // 40 KB: 10 neighbor embeddings
    __shared__ float  red[32][16][11];      // 22.5 KB: [seg][jl][k]
    __shared__ float  ured[32][17];         // u-partials for this block's 16 columns
    __shared__ float  scr[16][10];
    __shared__ float  redp[8];

    if (b == 64) {
        // ---- cnt-MLP finish -> dynamic_k (deterministic fixed-order + shfl tree) ----
        float s = 0.f;
        #pragma unroll 8
        for (int c = 0; c < 32; ++c) s += ws[WS_HP + c * HD + t];
        float v = fmaxf(s + bc1[t], 0.f) * Wc2[t];
        #pragma unroll
        for (int off = 32; off > 0; off >>= 1) v += __shfl_down(v, off);
        if (lane == 0) redp[wave] = v;
        __syncthreads();
        if (t == 0) {
            float z = bc2[0];
            #pragma unroll
            for (int w = 0; w < 8; ++w) z += redp[w];
            float frac = 1.f / (1.f + expf(-z));
            int dk = (int)floorf(frac * 10.f);
            ((int*)ws)[WS_DK] = dk < 1 ? 1 : (dk > 10 ? 10 : dk);
        }
        return;
    }

    // ---- column-GEMM: block owns j in [b*16, b*16+16), full K = 1024 of W1_bot ----
    const int jl  = t & 15;                 // local column
    const int seg = t >> 4;                 // row segment 0..31 (32 rows each)
    const int jg  = b * 16 + jl;

    if (t < 10) nb[t] = ((const int*)ws)[WS_NB + t];
    __syncthreads();
    #pragma unroll
    for (int i = t; i < 2560; i += 512) {   // stage 10 x 1024 floats as float4
        int k = i >> 8, c = i & 255;
        es4[k][c] = ((const float4*)(emb + (size_t)nb[k] * DD))[c];
    }
    ured[seg][jl] = ws[WS_UP + seg * DD + jg];   // one u-partial per thread
    __syncthreads();

    float acc[10];
    #pragma unroll
    for (int k = 0; k < 10; ++k) acc[k] = 0.f;
    const float* Wb = W1 + (size_t)(1024 + seg * 32) * DD + jg;
    for (int c = 0; c < 8; ++c) {
        float4 ev[10];
        #pragma unroll
        for (int k = 0; k < 10; ++k) ev[k] = es4[k][seg * 8 + c];   // same addr / 16 lanes: broadcast
        #pragma unroll
        for (int q = 0; q < 4; ++q) {
            const float wb = Wb[(size_t)(c * 4 + q) * DD];          // 16 consecutive j: 64B coalesced
            #pragma unroll
            for (int k = 0; k < 10; ++k)
                acc[k] += reinterpret_cast<const float*>(&ev[k])[q] * wb;
        }
    }
    #pragma unroll
    for (int k = 0; k < 10; ++k) red[seg][jl][k] = acc[k];
    __syncthreads();

    // per-(column,k) fixed-order segment reduction + u + relu + W2  (160 threads)
    if (t < 160) {
        const int k = t >> 4, jj = t & 15;
        float s = 0.f;
        #pragma unroll 8
        for (int g = 0; g < 32; ++g) s += red[g][jj][k];
        float u = 0.f;
        #pragma unroll 8
        for (int g = 0; g < 32; ++g) u += ured[g][jj];
        scr[jj][k] = fmaxf(u + s + ba1[b * 16 + jj], 0.f) * W2[b * 16 + jj];
    }
    __syncthreads();
    if (t < 10) {                            // fixed-order column sum, one atomicAdd per k
        float s = 0.f;
        #pragma unroll
        for (int c = 0; c < 16; ++c) s += scr[c][t];
        atomicAdd(&ws[WS_SC + t], s);
    }
}

// ============ K3: softmax + aggregate + outputs (1 block) ============
__global__ void __launch_bounds__(1024) k3(const float* __restrict__ emb,
                                           const float* __restrict__ ba2,
                                           float* __restrict__ ws,
                                           float* __restrict__ out) {
    const int t = threadIdx.x;              // 1024
    __shared__ float wl[10];
    __shared__ int   nb[10];
    if (t < 10) nb[t] = ((const int*)ws)[WS_NB + t];
    if (t == 0) {
        const int dk = ((const int*)ws)[WS_DK];
        float sv[10];
        float m = -INFINITY;
        for (int k = 0; k < 10; ++k) {
            float s = ws[WS_SC + k] + ba2[0];
            sv[k] = (k < dk) ? s : -INFINITY;
            if (sv[k] > m) m = sv[k];
        }
        float sum = 0.f;
        for (int k = 0; k < 10; ++k) { sv[k] = expf(sv[k] - m); sum += sv[k]; }
        for (int k = 0; k < 10; ++k) wl[k] = sv[k] / sum;
    }
    __syncthreads();
    float a = 0.f;
    #pragma unroll
    for (int k = 0; k < 10; ++k) a += wl[k] * emb[(size_t)nb[k] * DD + t];
    out[t] = a;
    if (t < 10) { out[1024 + t] = wl[t]; out[1044 + t] = wl[t]; }
}

extern "C" void kernel_launch(void* const* d_in, const int* in_sizes, int n_in,
                              void* d_out, int out_size, void* d_ws, size_t ws_size,
                              hipStream_t stream) {
    const float* x    = (const float*)d_in[0];   // target_embedding [1024]
    const float* emb  = (const float*)d_in[1];   // all_embeddings [16384,1024]
    const float* sim  = (const float*)d_in[2];   // similarity_matrix [16384,16384]
    const float* W1   = (const float*)d_in[3];   // W_att1 [2048,1024]
    const float* ba1  = (const float*)d_in[4];   // b_att1 [1024]
    const float* W2   = (const float*)d_in[5];   // W_att2 [1024]
    const float* ba2  = (const float*)d_in[6];   // b_att2 [1]
    const float* Wc1  = (const float*)d_in[7];   // W_cnt1 [1024,512]
    const float* bc1  = (const float*)d_in[8];   // b_cnt1 [512]
    const float* Wc2  = (const float*)d_in[9];   // W_cnt2 [512]
    const float* bc2  = (const float*)d_in[10];  // b_cnt2 [1]
    const int*   tidx = (const int*)d_in[11];    // target_idx [1]
    float* out = (float*)d_out;
    float* ws  = (float*)d_ws;

    hipLaunchKernelGGL(k1, dim3(97), dim3(512),  0, stream, x, W1, Wc1, sim, tidx, ws, out);
    hipLaunchKernelGGL(k2, dim3(65), dim3(512),  0, stream, emb, W1, ba1, W2, bc1, Wc2, bc2, ws);
    hipLaunchKernelGGL(k3, dim3(1),  dim3(1024), 0, stream, emb, ba2, ws, out);
}

// Round 10
// 37.997 us; speedup vs baseline: 1.0865x; 1.0027x over previous
//
#include <hip/hip_runtime.h>
#include <math.h>

#define NN 16384
#define DD 1024
#define HD 512

// ws layout (float units) — all plain stores, no zeroing needed anywhere:
// [4..14)   : (int)   nb[10]      (written by KA block 0; read by KB)
// [32..64)  : (float) zp[32]      cnt-MLP per-block partial z (KA blocks 64..95)
// [64..704) : (float) scp[64][10] per-block score partials (KA blocks 0..63)
#define WS_NB  4
#define WS_ZP  32
#define WS_SCP 64

// ============ KA: b0..63 = redundant top-11 + 16-col GEMM (u+v) + score partials;
//                  b64..95 = cnt-MLP column-complete slices ============
__global__ void __launch_bounds__(512) ka(const float* __restrict__ x,
                                          const float* __restrict__ emb,
                                          const float* __restrict__ sim,
                                          const float* __restrict__ W1,
                                          const float* __restrict__ ba1,
                                          const float* __restrict__ W2,
                                          const float* __restrict__ Wc1,
                                          const float* __restrict__ bc1,
                                          const float* __restrict__ Wc2,
                                          const int* __restrict__ tidx,
                                          float* __restrict__ ws,
                                          float* __restrict__ out) {
    const int t = threadIdx.x;              // 512
    const int b = blockIdx.x;               // 0..95
    const int lane = t & 63, wave = t >> 6;

    __shared__ float xsl[1024];

    if (b >= 64) {
        // ---- cnt-MLP slice c: hidden units [c*16, c*16+16) computed COMPLETELY,
        //      partial z plain-stored (deterministic fixed-order everywhere) ----
        __shared__ float credc[32][17];
        __shared__ float hs[16];
        const int c = b - 64;
        xsl[t] = x[t]; xsl[t + 512] = x[t + 512];
        __syncthreads();
        const int jl = t & 15, seg = t >> 4;        // 32 segs × 32 rows
        const int jg = c * 16 + jl;
        float a = 0.f;
        const float* Wc = Wc1 + (size_t)(seg * 32) * HD + jg;
        #pragma unroll 8
        for (int ii = 0; ii < 32; ++ii) a += xsl[seg * 32 + ii] * Wc[(size_t)ii * HD];
        credc[seg][jl] = a;
        __syncthreads();
        if (t < 16) {
            float s = 0.f;
            #pragma unroll 8
            for (int g = 0; g < 32; ++g) s += credc[g][t];
            hs[t] = fmaxf(s + bc1[c * 16 + t], 0.f) * Wc2[c * 16 + t];
        }
        __syncthreads();
        if (t == 0) {
            float z = 0.f;
            #pragma unroll
            for (int j = 0; j < 16; ++j) z += hs[j];
            ws[WS_ZP + c] = z;
        }
        return;
    }

    // ---- GEMM blocks: redundant deterministic top-11 (identical in every block) ----
    __shared__ float  wlv[8][11];
    __shared__ int    wli[8][11];
    __shared__ int    nbsh[10];
    __shared__ float4 es4[10][256];         // 40 KB
    __shared__ float  red[32][16][11];      // 22.5 KB: [seg][jl][k], slot 10 = u
    __shared__ float  scr[16][10];

    const int tgt = tidx[0];
    {
        const float4* row4 = (const float4*)(sim + (size_t)tgt * NN);
        float vals[32];
        #pragma unroll
        for (int c = 0; c < 8; ++c) {
            float4 v = row4[c * 512 + t];
            vals[c*4+0] = v.x; vals[c*4+1] = v.y; vals[c*4+2] = v.z; vals[c*4+3] = v.w;
        }
        // vals[s=c*4+q] holds row[gi], gi = c*2048 + t*4 + q (monotone in s for fixed t)
        unsigned used = 0u;
        float bv = -INFINITY; int bs = 0;
        #pragma unroll
        for (int s = 0; s < 32; ++s) if (vals[s] > bv) { bv = vals[s]; bs = s; }

        for (int it = 0; it < 11; ++it) {
            float cv = bv;
            int   cg2 = (bs >> 2) * 2048 + t * 4 + (bs & 3);
            #pragma unroll
            for (int off = 32; off > 0; off >>= 1) {
                float ov = __shfl_down(cv, off);
                int   og = __shfl_down(cg2, off);
                if (ov > cv || (ov == cv && og < cg2)) { cv = ov; cg2 = og; }
            }
            const int wg = __shfl(cg2, 0);      // broadcast winner to the wave
            if (lane == 0) { wlv[wave][it] = cv; wli[wave][it] = cg2; }
            if (((wg >> 2) & 511) == t) {       // owner: mask via bitmask, rescan (static idx)
                used |= 1u << (((wg >> 11) << 2) | (wg & 3));
                bv = -INFINITY; bs = 0;
                #pragma unroll
                for (int s = 0; s < 32; ++s) {
                    float v = ((used >> s) & 1u) ? -INFINITY : vals[s];
                    if (v > bv) { bv = v; bs = s; }
                }
            }
        }
        __syncthreads();
        if (t == 0) {
            // merge 8 sorted lists (val desc, idx asc), then stable compaction
            int head[8] = {0,0,0,0,0,0,0,0};
            int toplist[11];
            for (int it = 0; it < 11; ++it) {
                float fv = -INFINITY; int fg = 0x7fffffff; int fw = 0;
                #pragma unroll
                for (int w = 0; w < 8; ++w) {
                    float v = wlv[w][head[w]];
                    int   g = wli[w][head[w]];
                    if (v > fv || (v == fv && g < fg)) { fv = v; fg = g; fw = w; }
                }
                toplist[it] = fg;
                head[fw] = head[fw] < 10 ? head[fw] + 1 : 10;
            }
            int cnt = 0;
            for (int i = 0; i < 11 && cnt < 10; ++i) {
                int v = toplist[i];
                if (v != tgt) {
                    nbsh[cnt] = v;
                    if (b == 0) { ((int*)ws)[WS_NB + cnt] = v; out[1034 + cnt] = (float)v; }
                    ++cnt;
                }
            }
        }
    }
    xsl[t] = x[t]; xsl[t + 512] = x[t + 512];
    __syncthreads();                         // nbsh + xsl ready
    #pragma unroll
    for (int i = t; i < 2560; i += 512) {    // stage 10 × 1024 floats as float4
        int k = i >> 8, c = i & 255;
        es4[k][c] = ((const float4*)(emb + (size_t)nbsh[k] * DD))[c];
    }
    __syncthreads();

    // ---- 16-column GEMM over W1_top (u, slot 10) AND W1_bot (v_k), full K=1024 ----
    const int jl = t & 15, seg = t >> 4;     // seg owns 32 rows
    const int jg = b * 16 + jl;
    float acc[11];
    #pragma unroll
    for (int k = 0; k < 11; ++k) acc[k] = 0.f;
    const float* Wt = W1 + (size_t)(seg * 32) * DD + jg;
    const float* Wb = W1 + (size_t)(1024 + seg * 32) * DD + jg;
    for (int c = 0; c < 8; ++c) {
        float4 ev[10];
        #pragma unroll
        for (int k = 0; k < 10; ++k) ev[k] = es4[k][seg * 8 + c];  // same addr/16 lanes: broadcast
        #pragma unroll
        for (int q = 0; q < 4; ++q) {
            const int row = c * 4 + q;
            const float wt = Wt[(size_t)row * DD];                 // 16 consecutive j: coalesced
            const float wb = Wb[(size_t)row * DD];
            acc[10] += xsl[seg * 32 + row] * wt;
            #pragma unroll
            for (int k = 0; k < 10; ++k)
                acc[k] += reinterpret_cast<const float*>(&ev[k])[q] * wb;
        }
    }
    #pragma unroll
    for (int k = 0; k < 11; ++k) red[seg][jl][k] = acc[k];
    __syncthreads();

    // per-(column,k) fixed-order segment reduction + u + relu + W2  (160 threads)
    if (t < 160) {
        const int k = t >> 4, jj = t & 15;
        float s = 0.f, u = 0.f;
        #pragma unroll 8
        for (int g = 0; g < 32; ++g) { s += red[g][jj][k]; u += red[g][jj][10]; }
        scr[jj][k] = fmaxf(u + s + ba1[b * 16 + jj], 0.f) * W2[b * 16 + jj];
    }
    __syncthreads();
    if (t < 10) {                            // fixed-order column sum, PLAIN store (no atomics)
        float s = 0.f;
        #pragma unroll
        for (int c = 0; c < 16; ++c) s += scr[c][t];
        ws[WS_SCP + b * 10 + t] = s;
    }
}

// ============ KB: fixed-order reductions -> dk + scores; softmax; aggregate; outputs ============
__global__ void __launch_bounds__(1024) kb(const float* __restrict__ emb,
                                           const float* __restrict__ ba2,
                                           const float* __restrict__ bc2,
                                           float* __restrict__ ws,
                                           float* __restrict__ out) {
    const int t = threadIdx.x;              // 1024
    __shared__ float sred[10][65];
    __shared__ float zps[32];
    __shared__ float wl[10];
    __shared__ int   nb[10];
    if (t < 10) nb[t] = ((const int*)ws)[WS_NB + t];
    if (t < 32) zps[t] = ws[WS_ZP + t];
    if (t < 640) { const int k = t >> 6, g = t & 63; sred[k][g] = ws[WS_SCP + g * 10 + k]; }
    __syncthreads();
    // fixed-pairing tree over the 64 score partials per k (bitwise deterministic)
    for (int off = 32; off > 0; off >>= 1) {
        if (t < 640) { const int k = t >> 6, g = t & 63; if (g < off) sred[k][g] += sred[k][g + off]; }
        __syncthreads();
    }
    if (t == 0) {
        float z = bc2[0];
        #pragma unroll
        for (int c = 0; c < 32; ++c) z += zps[c];
        const float frac = 1.f / (1.f + expf(-z));
        int dk = (int)floorf(frac * 10.f);
        dk = dk < 1 ? 1 : (dk > 10 ? 10 : dk);
        float sv[10];
        float m = -INFINITY;
        for (int k = 0; k < 10; ++k) {
            float s = sred[k][0] + ba2[0];
            sv[k] = (k < dk) ? s : -INFINITY;
            if (sv[k] > m) m = sv[k];
        }
        float sum = 0.f;
        for (int k = 0; k < 10; ++k) { sv[k] = expf(sv[k] - m); sum += sv[k]; }
        for (int k = 0; k < 10; ++k) wl[k] = sv[k] / sum;
    }
    __syncthreads();
    float a = 0.f;
    #pragma unroll
    for (int k = 0; k < 10; ++k) a += wl[k] * emb[(size_t)nb[k] * DD + t];
    out[t] = a;
    if (t < 10) { out[1024 + t] = wl[t]; out[1044 + t] = wl[t]; }
}

extern "C" void kernel_launch(void* const* d_in, const int* in_sizes, int n_in,
                              void* d_out, int out_size, void* d_ws, size_t ws_size,
                              hipStream_t stream) {
    const float* x    = (const float*)d_in[0];   // target_embedding [1024]
    const float* emb  = (const float*)d_in[1];   // all_embeddings [16384,1024]
    const float* sim  = (const float*)d_in[2];   // similarity_matrix [16384,16384]
    const float* W1   = (const float*)d_in[3];   // W_att1 [2048,1024]
    const float* ba1  = (const float*)d_in[4];   // b_att1 [1024]
    const float* W2   = (const float*)d_in[5];   // W_att2 [1024]
    const float* ba2  = (const float*)d_in[6];   // b_att2 [1]
    const float* Wc1  = (const float*)d_in[7];   // W_cnt1 [1024,512]
    const float* bc1  = (const float*)d_in[8];   // b_cnt1 [512]
    const float* Wc2  = (const float*)d_in[9];   // W_cnt2 [512]
    const float* bc2  = (const float*)d_in[10];  // b_cnt2 [1]
    const int*   tidx = (const int*)d_in[11];    // target_idx [1]
    float* out = (float*)d_out;
    float* ws  = (float*)d_ws;

    hipLaunchKernelGGL(ka, dim3(96), dim3(512),  0, stream,
                       x, emb, sim, W1, ba1, W2, Wc1, bc1, Wc2, tidx, ws, out);
    hipLaunchKernelGGL(kb, dim3(1),  dim3(1024), 0, stream, emb, ba2, bc2, ws, out);
}